// Round 5
// baseline (1148.488 us; speedup 1.0000x reference)
//
#include <hip/hip_runtime.h>
#include <hip/hip_bf16.h>

typedef __bf16 bf16_t;
typedef __bf16 bf16x8 __attribute__((ext_vector_type(8)));
typedef __bf16 bf16x4 __attribute__((ext_vector_type(4)));
typedef float f32x4 __attribute__((ext_vector_type(4)));

#define QS   256.0f
#define QINV 0.00390625f

__device__ __forceinline__ void async_copy16(const bf16_t* g, bf16_t* l) {
  __builtin_amdgcn_global_load_lds(
      (__attribute__((address_space(1))) void*)g,
      (__attribute__((address_space(3))) void*)l,
      16, 0, 0);
}

// C = quantize-epilogue(A @ Bt^T + bias)
// A:  [M][K] bf16 row-major; Bt: [N][K] bf16 row-major (B transposed)
// 16x16x32 MFMA, wave computes 64x64 as 4x4 tiles of 16x16.
// LDS XOR swizzle: 16B chunk c of row r stored at phys chunk c ^ (r & 7)
// (staged by permuting which GLOBAL chunk each lane fetches) ->
// ds_read_b128 fragment reads are bank-conflict-free (verified: R2/R4
// SQ_LDS_BANK_CONFLICT = 0).
// GELU PWL: 64-entry register table (lane l holds y(x_l), slope_l);
// branchless — out-of-range xq extrapolates correctly through the table
// tails (left tail slopes ~3e-5 round to 0; right tail is ~identity,
// interp error * 256 < 0.5 so quantization is exact).
// XCD swizzle: flat dispatch id & 7 = XCD on MI355X; give each XCD a
// contiguous band of 16 M-row panels so A-panels stay in one L2.
// Dims are template constants -> staging address chains strength-reduced.
template <bool GELU, typename OutT, int GX, int M, int N, int K>
__global__ __launch_bounds__(256, 5)
void gemm_tile(const bf16_t* __restrict__ A, const bf16_t* __restrict__ Bt,
               const float* __restrict__ bias, OutT* __restrict__ C) {
  __shared__ __attribute__((aligned(16))) bf16_t As[128 * 64];
  __shared__ __attribute__((aligned(16))) bf16_t Bs[128 * 64];

  const int tid = threadIdx.x;
  const int lane = tid & 63;
  const int wv = tid >> 6;
  const int wy = wv >> 1;   // wave row (0/1) -> 64 rows
  const int wx = wv & 1;    // wave col (0/1) -> 64 cols
  const int l15 = lane & 15;
  const int lq = lane >> 4; // quad 0..3

  // register-resident PWL table: lane l holds y(x_l) and slope to x_{l+1}
  // (x_l = -4 + 0.25*l, l in [0,64) -> covers xq in [-4, 12) exactly,
  // extrapolates safely outside)
  float ytA = 0.f, ytS = 0.f;
  if (GELU) {
    float xv = -4.0f + 0.25f * (float)lane;
    float y0 = 0.5f * xv * (1.0f + erff(xv * 0.70710678f));
    float xv1 = xv + 0.25f;
    float y1 = 0.5f * xv1 * (1.0f + erff(xv1 * 0.70710678f));
    ytA = y0;
    ytS = y1 - y0;
  }

  // XCD-locality block swizzle (grid = GX x (M/128), M/128 == 128)
  const int f = blockIdx.y * GX + blockIdx.x;
  const int xcd = f & 7;
  const int s = f >> 3;
  const int bx = s % GX;                       // GX is a power of two
  const int by = xcd * ((M / 128) / 8) + s / GX;

  const int mBase = by * 128;
  const int nBase = bx * 128;

  f32x4 acc[4][4];
#pragma unroll
  for (int i = 0; i < 4; ++i)
#pragma unroll
    for (int j = 0; j < 4; ++j)
      acc[i][j] = (f32x4){0.f, 0.f, 0.f, 0.f};

  const int srow = tid >> 3;                              // 0..31 (row within 32-row pass)
  const int scb = (((tid & 7) ^ ((tid >> 3) & 7)) * 8);   // swizzled global chunk for this lane

  const bf16_t* aPtr = A + (size_t)(mBase + srow) * K + scb;
  const bf16_t* bPtr = Bt + (size_t)(nBase + srow) * K + scb;

  // read-side swizzle: physical chunk = (ks*4 + lq) ^ (l15 & 7)
  const int swz_r = l15 & 7;

  for (int k0 = 0; k0 < K; k0 += 64) {
    // ---- stage A,B tiles (128 x 64 bf16 each) via async global->LDS, 16B/lane
#pragma unroll
    for (int p = 0; p < 4; ++p) {
      const int lo = (p * 256 + wv * 64) * 8;  // wave-uniform segment base (elements)
      async_copy16(aPtr + (size_t)p * 32 * K + k0, As + lo);
      async_copy16(bPtr + (size_t)p * 32 * K + k0, Bs + lo);
    }
    __syncthreads();  // drains vmcnt: tiles resident

    // ---- compute: 2 k-substeps of 32, 16 MFMA each per wave
#pragma unroll
    for (int ks = 0; ks < 2; ++ks) {
      const int swzA = ((ks * 4 + lq) ^ swz_r) * 8;  // physical chunk offset (elements)
      bf16x8 af[4], bfr[4];
#pragma unroll
      for (int i = 0; i < 4; ++i) {
        af[i]  = *(const bf16x8*)(As + (wy * 64 + i * 16 + l15) * 64 + swzA);
        bfr[i] = *(const bf16x8*)(Bs + (wx * 64 + i * 16 + l15) * 64 + swzA);
      }
#pragma unroll
      for (int i = 0; i < 4; ++i)
#pragma unroll
        for (int j = 0; j < 4; ++j)
          acc[i][j] = __builtin_amdgcn_mfma_f32_16x16x32_bf16(af[i], bfr[j], acc[i][j], 0, 0, 0);
    }
    __syncthreads();  // all waves done reading before next stage
  }

  // ---- epilogue: bias + quantize (+ branchless PWL GELU via register table)
  float bj[4];
#pragma unroll
  for (int j = 0; j < 4; ++j)
    bj[j] = bias[nBase + wx * 64 + j * 16 + l15];

#pragma unroll
  for (int i = 0; i < 4; ++i) {
    const int rb = mBase + wy * 64 + i * 16 + lq * 4;
#pragma unroll
    for (int j = 0; j < 4; ++j) {
      const int cn = nBase + wx * 64 + j * 16 + l15;
#pragma unroll
      for (int r = 0; r < 4; ++r) {
        float c = acc[i][j][r] + bj[j];
        float v;
        if (GELU) {
          float rq = rintf(c * QS);                  // xq = rq/256 (Positional_0)
          float t = fmaf(rq, 0.015625f, 16.0f);      // (xq+4)*4 exactly
          int ii = (int)t;                            // trunc; table idx
          ii = ii < 0 ? 0 : ii;                       // left-tail clamp only
          float fr = t - (float)ii;
          float y0 = __shfl(ytA, ii);
          float sl = __shfl(ytS, ii);
          v = fmaf(fr, sl, y0);
          v = rintf(v * QS) * QINV;                  // quantize out (Positional_1 idempotent)
        } else {
          v = rintf(c * QS) * QINV;                  // Positional_2
        }
        C[(size_t)(rb + r) * N + cn] = (OutT)v;
      }
    }
  }
}

// merged preprocessing: x->bf16 cvt, w1 transpose+cvt, w2 transpose+cvt
// blocks [0,16384): cvt (256 float4 each)
// blocks [16384,20480): w1 [1024][4096] -> w1t [4096][1024]
// blocks [20480,24576): w2 [4096][1024] -> w2t [1024][4096]
__global__ void prep_kernel(const float* __restrict__ x,
                            const float* __restrict__ w1,
                            const float* __restrict__ w2,
                            bf16_t* __restrict__ xb,
                            bf16_t* __restrict__ w1t,
                            bf16_t* __restrict__ w2t) {
  __shared__ float t[32][33];
  const int b = blockIdx.x;
  const int tid = threadIdx.x;
  if (b < 16384) {
    const int idx = b * 256 + tid;  // < 16384*1024/4 exactly
    const float4 v = ((const float4*)x)[idx];
    bf16x4 o;
    o[0] = (bf16_t)v.x; o[1] = (bf16_t)v.y; o[2] = (bf16_t)v.z; o[3] = (bf16_t)v.w;
    ((bf16x4*)xb)[idx] = o;
    return;
  }
  const float* in;
  bf16_t* out;
  int R, C, bxx, byy;
  if (b < 20480) {
    const int rb = b - 16384;
    in = w1; out = w1t; R = 1024; C = 4096;
    bxx = rb & 127; byy = rb >> 7;   // grid (128, 32)
  } else {
    const int rb = b - 20480;
    in = w2; out = w2t; R = 4096; C = 1024;
    bxx = rb & 31; byy = rb >> 5;    // grid (32, 128)
  }
  const int c0 = bxx * 32;
  const int r0 = byy * 32;
  const int tx = tid & 31;
  const int ty = tid >> 5;  // 0..7
#pragma unroll
  for (int dy = 0; dy < 32; dy += 8)
    t[ty + dy][tx] = in[(size_t)(r0 + ty + dy) * C + c0 + tx];
  __syncthreads();
#pragma unroll
  for (int dy = 0; dy < 32; dy += 8)
    out[(size_t)(c0 + ty + dy) * R + r0 + tx] = (bf16_t)t[tx][ty + dy];
}

extern "C" void kernel_launch(void* const* d_in, const int* in_sizes, int n_in,
                              void* d_out, int out_size, void* d_ws, size_t ws_size,
                              hipStream_t stream) {
  const float* x  = (const float*)d_in[0];   // [32,512,1024] = [16384][1024]
  const float* w1 = (const float*)d_in[1];   // [1024][4096]
  const float* b1 = (const float*)d_in[2];   // [4096]
  const float* w2 = (const float*)d_in[3];   // [4096][1024]
  const float* b2 = (const float*)d_in[4];   // [1024]
  float* out = (float*)d_out;                // [16384][1024]

  constexpr int M = 16384, D = 1024, F = 4096;

  char* ws = (char*)d_ws;
  size_t off = 0;
  bf16_t* xb  = (bf16_t*)(ws + off); off += (size_t)M * D * 2;  // 33.5 MB
  bf16_t* w1t = (bf16_t*)(ws + off); off += (size_t)D * F * 2;  //  8.4 MB
  bf16_t* w2t = (bf16_t*)(ws + off); off += (size_t)F * D * 2;  //  8.4 MB
  bf16_t* h   = (bf16_t*)(ws + off);                            // 134.2 MB

  prep_kernel<<<24576, 256, 0, stream>>>(x, w1, w2, xb, w1t, w2t);

  // GEMM1 + quantize + PWL-GELU + quantize -> h (bf16)
  gemm_tile<true, bf16_t, F / 128, M, F, D>
      <<<dim3(F / 128, M / 128), 256, 0, stream>>>(xb, w1t, b1, h);
  // GEMM2 + quantize -> out (f32)
  gemm_tile<false, float, D / 128, M, D, F>
      <<<dim3(D / 128, M / 128), 256, 0, stream>>>(h, w2t, b2, out);
}

// Round 6
// 433.081 us; speedup vs baseline: 2.6519x; 2.6519x over previous
//
#include <hip/hip_runtime.h>
#include <hip/hip_bf16.h>

typedef __bf16 bf16_t;
typedef __bf16 bf16x8 __attribute__((ext_vector_type(8)));
typedef __bf16 bf16x4 __attribute__((ext_vector_type(4)));
typedef float f32x4 __attribute__((ext_vector_type(4)));

#define QS   256.0f
#define QINV 0.00390625f

__device__ __forceinline__ void async_copy16(const bf16_t* g, bf16_t* l) {
  __builtin_amdgcn_global_load_lds(
      (__attribute__((address_space(1))) void*)g,
      (__attribute__((address_space(3))) void*)l,
      16, 0, 0);
}

// C = quantize-epilogue(A @ Bt^T + bias)
// A:  [M][K] bf16 row-major; Bt: [N][K] bf16 row-major (B transposed)
// 16x16x32 MFMA, wave computes 64x64 as 4x4 tiles of 16x16.
// LDS XOR swizzle: 16B chunk c of row r stored at phys chunk c ^ (r & 7)
// -> ds_read_b128 fragment reads bank-conflict-free (R2/R4: conflicts = 0).
// GELU PWL: 64-entry register table (lane l holds y(x_l), slope_l);
// branchless — tails extrapolate correctly through the table
// (left-tail slopes ~3e-5 round to 0; right tail ~identity, interp
// error * 256 < 0.5 so output quantization is exact).
// XCD swizzle: flat dispatch id & 7 = XCD on MI355X; each XCD gets a
// contiguous band of M-row panels so A-panels stay in one L2.
// __launch_bounds__(256,4): DO NOT raise to 5 — the 512/5=102-VGPR budget
// spills the 64-reg accumulator to scratch (R5: 2.2 GB HBM traffic/dispatch,
// 527 us). (256,4) gives VGPR=64, zero spill.
template <bool GELU, typename OutT, int GX, int M, int N, int K>
__global__ __launch_bounds__(256, 4)
void gemm_tile(const bf16_t* __restrict__ A, const bf16_t* __restrict__ Bt,
               const float* __restrict__ bias, OutT* __restrict__ C) {
  __shared__ __attribute__((aligned(16))) bf16_t As[128 * 64];
  __shared__ __attribute__((aligned(16))) bf16_t Bs[128 * 64];

  const int tid = threadIdx.x;
  const int lane = tid & 63;
  const int wv = tid >> 6;
  const int wy = wv >> 1;   // wave row (0/1) -> 64 rows
  const int wx = wv & 1;    // wave col (0/1) -> 64 cols
  const int l15 = lane & 15;
  const int lq = lane >> 4; // quad 0..3

  // register-resident PWL table: lane l holds y(x_l) and slope to x_{l+1}
  // (x_l = -4 + 0.25*l, l in [0,64) -> covers xq in [-4, 12) exactly)
  float ytA = 0.f, ytS = 0.f;
  if (GELU) {
    float xv = -4.0f + 0.25f * (float)lane;
    float y0 = 0.5f * xv * (1.0f + erff(xv * 0.70710678f));
    float xv1 = xv + 0.25f;
    float y1 = 0.5f * xv1 * (1.0f + erff(xv1 * 0.70710678f));
    ytA = y0;
    ytS = y1 - y0;
  }

  // XCD-locality block swizzle (grid = GX x (M/128), M/128 == 128)
  const int f = blockIdx.y * GX + blockIdx.x;
  const int xcd = f & 7;
  const int s = f >> 3;
  const int bx = s % GX;                       // GX is a power of two
  const int by = xcd * ((M / 128) / 8) + s / GX;

  const int mBase = by * 128;
  const int nBase = bx * 128;

  f32x4 acc[4][4];
#pragma unroll
  for (int i = 0; i < 4; ++i)
#pragma unroll
    for (int j = 0; j < 4; ++j)
      acc[i][j] = (f32x4){0.f, 0.f, 0.f, 0.f};

  const int srow = tid >> 3;                              // 0..31 (row within 32-row pass)
  const int scb = (((tid & 7) ^ ((tid >> 3) & 7)) * 8);   // swizzled global chunk for this lane

  const bf16_t* aPtr = A + (size_t)(mBase + srow) * K + scb;
  const bf16_t* bPtr = Bt + (size_t)(nBase + srow) * K + scb;

  // read-side swizzle: physical chunk = (ks*4 + lq) ^ (l15 & 7)
  const int swz_r = l15 & 7;

  for (int k0 = 0; k0 < K; k0 += 64) {
    // ---- stage A,B tiles (128 x 64 bf16 each) via async global->LDS, 16B/lane
#pragma unroll
    for (int p = 0; p < 4; ++p) {
      const int lo = (p * 256 + wv * 64) * 8;  // wave-uniform segment base (elements)
      async_copy16(aPtr + (size_t)p * 32 * K + k0, As + lo);
      async_copy16(bPtr + (size_t)p * 32 * K + k0, Bs + lo);
    }
    __syncthreads();  // drains vmcnt: tiles resident

    // ---- compute: 2 k-substeps of 32, 16 MFMA each per wave
#pragma unroll
    for (int ks = 0; ks < 2; ++ks) {
      const int swzA = ((ks * 4 + lq) ^ swz_r) * 8;  // physical chunk offset (elements)
      bf16x8 af[4], bfr[4];
#pragma unroll
      for (int i = 0; i < 4; ++i) {
        af[i]  = *(const bf16x8*)(As + (wy * 64 + i * 16 + l15) * 64 + swzA);
        bfr[i] = *(const bf16x8*)(Bs + (wx * 64 + i * 16 + l15) * 64 + swzA);
      }
#pragma unroll
      for (int i = 0; i < 4; ++i)
#pragma unroll
        for (int j = 0; j < 4; ++j)
          acc[i][j] = __builtin_amdgcn_mfma_f32_16x16x32_bf16(af[i], bfr[j], acc[i][j], 0, 0, 0);
    }
    __syncthreads();  // all waves done reading before next stage
  }

  // ---- epilogue: bias + quantize (+ branchless PWL GELU via register table)
  float bj[4];
#pragma unroll
  for (int j = 0; j < 4; ++j)
    bj[j] = bias[nBase + wx * 64 + j * 16 + l15];

#pragma unroll
  for (int i = 0; i < 4; ++i) {
    const int rb = mBase + wy * 64 + i * 16 + lq * 4;
#pragma unroll
    for (int j = 0; j < 4; ++j) {
      const int cn = nBase + wx * 64 + j * 16 + l15;
#pragma unroll
      for (int r = 0; r < 4; ++r) {
        float c = acc[i][j][r] + bj[j];
        float v;
        if (GELU) {
          float rq = rintf(c * QS);                  // xq = rq/256 (Positional_0)
          float t = fmaf(rq, 0.015625f, 16.0f);      // (xq+4)*4 exactly
          int ii = (int)t;                            // trunc; table idx
          ii = ii < 0 ? 0 : ii;                       // left-tail clamp only
          float fr = t - (float)ii;
          float y0 = __shfl(ytA, ii);
          float sl = __shfl(ytS, ii);
          v = fmaf(fr, sl, y0);
          v = rintf(v * QS) * QINV;                  // quantize out (Positional_1 idempotent)
        } else {
          v = rintf(c * QS) * QINV;                  // Positional_2
        }
        C[(size_t)(rb + r) * N + cn] = (OutT)v;
      }
    }
  }
}

// merged preprocessing: x->bf16 cvt, w1 transpose+cvt, w2 transpose+cvt
// blocks [0,16384): cvt (256 float4 each)
// blocks [16384,20480): w1 [1024][4096] -> w1t [4096][1024]
// blocks [20480,24576): w2 [4096][1024] -> w2t [1024][4096]
__global__ void prep_kernel(const float* __restrict__ x,
                            const float* __restrict__ w1,
                            const float* __restrict__ w2,
                            bf16_t* __restrict__ xb,
                            bf16_t* __restrict__ w1t,
                            bf16_t* __restrict__ w2t) {
  __shared__ float t[32][33];
  const int b = blockIdx.x;
  const int tid = threadIdx.x;
  if (b < 16384) {
    const int idx = b * 256 + tid;  // < 16384*1024/4 exactly
    const float4 v = ((const float4*)x)[idx];
    bf16x4 o;
    o[0] = (bf16_t)v.x; o[1] = (bf16_t)v.y; o[2] = (bf16_t)v.z; o[3] = (bf16_t)v.w;
    ((bf16x4*)xb)[idx] = o;
    return;
  }
  const float* in;
  bf16_t* out;
  int R, C, bxx, byy;
  if (b < 20480) {
    const int rb = b - 16384;
    in = w1; out = w1t; R = 1024; C = 4096;
    bxx = rb & 127; byy = rb >> 7;   // grid (128, 32)
  } else {
    const int rb = b - 20480;
    in = w2; out = w2t; R = 4096; C = 1024;
    bxx = rb & 31; byy = rb >> 5;    // grid (32, 128)
  }
  const int c0 = bxx * 32;
  const int r0 = byy * 32;
  const int tx = tid & 31;
  const int ty = tid >> 5;  // 0..7
#pragma unroll
  for (int dy = 0; dy < 32; dy += 8)
    t[ty + dy][tx] = in[(size_t)(r0 + ty + dy) * C + c0 + tx];
  __syncthreads();
#pragma unroll
  for (int dy = 0; dy < 32; dy += 8)
    out[(size_t)(c0 + ty + dy) * R + r0 + tx] = (bf16_t)t[tx][ty + dy];
}

extern "C" void kernel_launch(void* const* d_in, const int* in_sizes, int n_in,
                              void* d_out, int out_size, void* d_ws, size_t ws_size,
                              hipStream_t stream) {
  const float* x  = (const float*)d_in[0];   // [32,512,1024] = [16384][1024]
  const float* w1 = (const float*)d_in[1];   // [1024][4096]
  const float* b1 = (const float*)d_in[2];   // [4096]
  const float* w2 = (const float*)d_in[3];   // [4096][1024]
  const float* b2 = (const float*)d_in[4];   // [1024]
  float* out = (float*)d_out;                // [16384][1024]

  constexpr int M = 16384, D = 1024, F = 4096;

  char* ws = (char*)d_ws;
  size_t off = 0;
  bf16_t* xb  = (bf16_t*)(ws + off); off += (size_t)M * D * 2;  // 33.5 MB
  bf16_t* w1t = (bf16_t*)(ws + off); off += (size_t)D * F * 2;  //  8.4 MB
  bf16_t* w2t = (bf16_t*)(ws + off); off += (size_t)F * D * 2;  //  8.4 MB
  bf16_t* h   = (bf16_t*)(ws + off);                            // 134.2 MB

  prep_kernel<<<24576, 256, 0, stream>>>(x, w1, w2, xb, w1t, w2t);

  // GEMM1 + quantize + PWL-GELU + quantize -> h (bf16)
  gemm_tile<true, bf16_t, F / 128, M, F, D>
      <<<dim3(F / 128, M / 128), 256, 0, stream>>>(xb, w1t, b1, h);
  // GEMM2 + quantize -> out (f32)
  gemm_tile<false, float, D / 128, M, D, F>
      <<<dim3(D / 128, M / 128), 256, 0, stream>>>(h, w2t, b2, out);
}